// Round 9
// baseline (807.544 us; speedup 1.0000x reference)
//
#include <hip/hip_runtime.h>

// Self-attention fwd: B=4, S=2048, D=1024, single head.
// Round 17: re-test R14's gemmW (256x128 block, wave 128x64, 3 blocks/CU,
// 34.3 B/KFLOP LDS traffic) with the L2-thrash cause REMOVED.
//   R14's 462MB FETCH was grid-order: round-robin XCD assignment gave each
//   XCD a strided sample of all panels (working set >> 4MB L2). Fix: T1
//   bijective XCD swizzle (all grids %8==0): XCD k executes a CONTIGUOUS
//   x-fastest work range -> per-XCD instantaneous set ~ shared A-panel +
//   ~12 B-tiles ~ 3.5MB <= 4MB.
//   R16 falsified entry-stagger at 2/CU; R13 shown ~LDS-unit-bound with
//   partial overlap. gemmW attacks both: fewer LDS bytes/FLOP + 3 blocks/CU
//   so MFMA of one block fills under another's LDS stream (single-buffered
//   vmcnt(0) latency covered by the other two blocks).
//   Stagger by capacity-wave ((rawlin>>8)%3) seeds anti-phase (free).
// PV keeps the R13-proven gemm4w 128x128 2/CU kernel (+ swizzle only).
// Epilogues + associativity rewrite out = P @ (V*Wo) kept.
//
// ws layout (bf16-element offsets over (u16*)d_ws):
//   xb    @ 0          (8388608)   <- VWoT after QKV (xb dead)  [b][do][s]
//   qkv   @ 8388608    (25165824)  [8192][3072] (q|k|v interleaved by col)
//   E     @ 33554432   (16777216)  exp(logits) bf16
//   wqkvT @ 50331648   (3145728)   [3072][1024]  (wqT|wkT|wvT)
//   woT   @ 53477376   (1048576)
//   bqkv  @ 54525952   (6144 u16 = 3072 fp32)
//   l     @ 54532096   (16384 u16 = 8192 fp32 row sums)   end = 109.1 MB

typedef unsigned short u16;
typedef short bf16x8 __attribute__((ext_vector_type(8)));
typedef float f32x4 __attribute__((ext_vector_type(4)));

#define SEQ 2048
#define DIM 1024

__device__ __forceinline__ u16 f2bf(float f) {
    unsigned u = __builtin_bit_cast(unsigned, f);
    u += 0x7fffu + ((u >> 16) & 1u);
    return (u16)(u >> 16);
}

// async 16B global -> LDS (wave-uniform LDS base + lane*16 by construction)
__device__ __forceinline__ void async16(void* lds, const void* gmem) {
    __builtin_amdgcn_global_load_lds(
        (const __attribute__((address_space(1))) void*)gmem,
        (__attribute__((address_space(3))) void*)lds, 16, 0, 0);
}

#define FENCE() asm volatile("" ::: "memory")

// ---------------------------------------------------------------------------
// cast x fp32 -> bf16 (blocks 0..8191); bias concat + zero l (blocks 8192+)
__global__ __launch_bounds__(256) void cast_x_kernel(
    const float* __restrict__ x, u16* __restrict__ xb,
    const float* __restrict__ bq, const float* __restrict__ bk,
    const float* __restrict__ bv, float* __restrict__ bqkv,
    float* __restrict__ l)
{
    const int b = blockIdx.x;
    if (b < 8192) {
        const int idx = b * 256 + threadIdx.x;
        float4 v = ((const float4*)x)[idx];
        ushort4 o;
        o.x = f2bf(v.x); o.y = f2bf(v.y); o.z = f2bf(v.z); o.w = f2bf(v.w);
        ((ushort4*)xb)[idx] = o;
    } else {
        const int i = (b - 8192) * 256 + threadIdx.x;   // 0..11263
        if (i < 3072)
            bqkv[i] = (i < 1024) ? bq[i] : (i < 2048) ? bk[i - 1024] : bv[i - 2048];
        else if (i < 3072 + 8192)
            l[i - 3072] = 0.f;
    }
}

// transpose+cast all four 1024x1024 fp32 weights -> bf16 WT[n][k]; z picks W.
__global__ __launch_bounds__(256) void transpose_cast_all(
    const float* __restrict__ W0, const float* __restrict__ W1,
    const float* __restrict__ W2, const float* __restrict__ W3,
    u16* __restrict__ Tqkv, u16* __restrict__ To)
{
    __shared__ float tile[32][33];
    const int z = blockIdx.z;
    const float* W = (z == 0) ? W0 : (z == 1) ? W1 : (z == 2) ? W2 : W3;
    u16* T = (z < 3) ? (Tqkv + (size_t)z * 1048576) : To;

    const int bx = blockIdx.x * 32, by = blockIdx.y * 32;
    const int tx = threadIdx.x, ty = threadIdx.y;
    #pragma unroll
    for (int r = 0; r < 4; ++r)
        tile[ty + r * 8][tx] = W[(size_t)(by + ty + r * 8) * DIM + bx + tx];
    __syncthreads();
    #pragma unroll
    for (int r = 0; r < 4; ++r) {
        const float v = tile[tx][ty + r * 8];   // = W[by+tx][bx+ty+r*8]
        T[(size_t)(bx + ty + r * 8) * DIM + by + tx] = f2bf(v);
    }
}

// ---------------------------------------------------------------------------
#define EPI_BF16BIAS 0  // bf16 store of a+bias[col]
#define EPI_BF16     1  // bf16 store of a
#define EPI_ELOGIT   2  // store exp(a*scale) bf16 + atomic row sums into lsum
#define EPI_PVOUT    3  // fp32 store of a/lsum[row] + bias[col]

// bijective XCD swizzle (TOT % 8 == 0): hardware id rawlin (round-robin over
// XCDs) -> work id w such that XCD k executes the contiguous x-fastest range
// [k*TOT/8, (k+1)*TOT/8)  => per-XCD L2 working set = one A-panel + few
// B-tiles instead of a strided sample of everything.
template<int GX, int GY, int GZ>
__device__ __forceinline__ void swz_work(int& bx, int& by, int& bz, int& rawlin) {
    constexpr int TOT = GX * GY * GZ;
    static_assert(TOT % 8 == 0, "grid must be divisible by 8");
    rawlin = blockIdx.x + GX * (blockIdx.y + GY * blockIdx.z);
    const int w = (rawlin & 7) * (TOT / 8) + (rawlin >> 3);
    bx = w % GX;
    by = (w / GX) % GY;
    bz = w / (GX * GY);
}

// ---------------------------------------------------------------------------
// gemmW: 256x128-tile, 4 waves, wave 128x64 (acc 8x4), BK=64 single-buffered
// LDS (48 KB -> 3 blocks/CU). A[M,K] @ Bt[N,K]^T.
template<int EPI, int K, int LDA, int LDB, int LDC, int GX, int GY, int GZ>
__global__ __launch_bounds__(256, 3) void gemmW(
    const u16* __restrict__ A, const u16* __restrict__ Bt,
    const float* __restrict__ bias, u16* __restrict__ C,
    float* __restrict__ Cf, float* __restrict__ lsum,
    float scale, long sA, long sB, long sC)
{
    __shared__ u16 sAt[256 * 64];   // 32 KB
    __shared__ u16 sBt[128 * 64];   // 16 KB

    constexpr int NT = K / 64;

    int bx, by, z, rawlin;
    swz_work<GX, GY, GZ>(bx, by, z, rawlin);

    const int t = threadIdx.x;                 // 0..255
    const int wid = t >> 6, lane = t & 63;
    const int wm = wid >> 1, wn = wid & 1;     // wave tile: 128x64 at (wm,wn)
    const int lrow = lane & 15, quad = lane >> 4;
    const int m0 = by * 256, n0 = bx * 128;

    // anti-lockstep stagger by capacity wave (~0/450/900 cyc)
    const int slot = (rawlin >> 8) % 3;
    if (slot > 0) __builtin_amdgcn_s_sleep(7);
    if (slot > 1) __builtin_amdgcn_s_sleep(7);

    const u16* ABase = A  + (size_t)z * sA + (size_t)m0 * LDA;
    const u16* BBase = Bt + (size_t)z * sB + (size_t)n0 * LDB;

    // staging: A 2048 16B-chunks (8/thread), B 1024 (4/thread). LDS dest is
    // linear; global SOURCE chunk is pre-swizzled with the read involution
    // chunk ^= (row&7)  (byte bits 4-6 ^= row bits 0-2; rows are 128 B).
    int offA[8], offB[4];
    #pragma unroll
    for (int p = 0; p < 8; ++p) {
        const int s = p * 256 + t, row = s >> 3, c8 = (s & 7) ^ (row & 7);
        offA[p] = row * LDA + c8 * 8;
    }
    #pragma unroll
    for (int p = 0; p < 4; ++p) {
        const int s = p * 256 + t, row = s >> 3, c8 = (s & 7) ^ (row & 7);
        offB[p] = row * LDB + c8 * 8;
    }

    f32x4 acc[8][4];
    #pragma unroll
    for (int i = 0; i < 8; ++i)
        #pragma unroll
        for (int j = 0; j < 4; ++j)
            acc[i][j] = (f32x4){0.f, 0.f, 0.f, 0.f};

    auto ldA1 = [&](int mi, int ks) -> bf16x8 {
        int b = (wm * 128 + mi * 16 + lrow) * 128 + ks * 64 + quad * 16;
        b ^= ((b >> 7) & 7) << 4;
        return *(const bf16x8*)((const char*)sAt + b);
    };
    auto ldB1 = [&](int ni, int ks) -> bf16x8 {
        int b = (wn * 64 + ni * 16 + lrow) * 128 + ks * 64 + quad * 16;
        b ^= ((b >> 7) & 7) << 4;
        return *(const bf16x8*)((const char*)sBt + b);
    };

    #pragma unroll 1
    for (int T = 0; T < NT; ++T) {
        const int k0 = T * 64;
        #pragma unroll
        for (int p = 0; p < 8; ++p)
            async16(&sAt[(p * 256 + t) * 8], ABase + k0 + offA[p]);
        #pragma unroll
        for (int p = 0; p < 4; ++p)
            async16(&sBt[(p * 256 + t) * 8], BBase + k0 + offB[p]);
        asm volatile("s_waitcnt vmcnt(0)" ::: "memory");
        __builtin_amdgcn_s_barrier();

        #pragma unroll
        for (int ks = 0; ks < 2; ++ks) {
            bf16x8 aF[8], bF[4];
            #pragma unroll
            for (int mi = 0; mi < 8; ++mi) aF[mi] = ldA1(mi, ks);
            #pragma unroll
            for (int ni = 0; ni < 4; ++ni) bF[ni] = ldB1(ni, ks);
            __builtin_amdgcn_s_setprio(1);
            #pragma unroll
            for (int mi = 0; mi < 8; ++mi)
                #pragma unroll
                for (int ni = 0; ni < 4; ++ni)
                    acc[mi][ni] = __builtin_amdgcn_mfma_f32_16x16x32_bf16(
                        aF[mi], bF[ni], acc[mi][ni], 0, 0, 0);
            __builtin_amdgcn_s_setprio(0);
        }
        FENCE();
        __builtin_amdgcn_s_barrier();  // all reads consumed -> next stage safe
    }

    // ---- epilogue ----
    u16*   Cz  = C  + (size_t)z * sC;
    float* Cfz = Cf ? Cf + (size_t)z * sC : nullptr;

    #pragma unroll
    for (int mi = 0; mi < 8; ++mi) {
        const int row = m0 + wm * 128 + mi * 16 + quad * 4;  // rows row..row+3
        if (EPI == EPI_BF16BIAS) {
            #pragma unroll
            for (int ni = 0; ni < 4; ++ni) {
                const int col = n0 + wn * 64 + ni * 16 + lrow;
                const float bb = bias[col];
                const f32x4 a = acc[mi][ni];
                #pragma unroll
                for (int r = 0; r < 4; ++r)
                    Cz[(size_t)(row + r) * LDC + col] = f2bf(a[r] + bb);
            }
        } else if (EPI == EPI_BF16) {
            #pragma unroll
            for (int ni = 0; ni < 4; ++ni) {
                const int col = n0 + wn * 64 + ni * 16 + lrow;
                const f32x4 a = acc[mi][ni];
                #pragma unroll
                for (int r = 0; r < 4; ++r)
                    Cz[(size_t)(row + r) * LDC + col] = f2bf(a[r]);
            }
        } else if (EPI == EPI_ELOGIT) {
            float rs[4] = {0.f, 0.f, 0.f, 0.f};
            #pragma unroll
            for (int ni = 0; ni < 4; ++ni) {
                const int col = n0 + wn * 64 + ni * 16 + lrow;
                const f32x4 a = acc[mi][ni];
                #pragma unroll
                for (int r = 0; r < 4; ++r) {
                    const float e = __expf(a[r] * scale);
                    Cz[(size_t)(row + r) * LDC + col] = f2bf(e);
                    rs[r] += e;
                }
            }
            #pragma unroll
            for (int r = 0; r < 4; ++r) {
                float s = rs[r];
                s += __shfl_xor(s, 1, 64);
                s += __shfl_xor(s, 2, 64);
                s += __shfl_xor(s, 4, 64);
                s += __shfl_xor(s, 8, 64);
                if (lrow == 0)
                    atomicAdd(&lsum[(size_t)z * 2048 + row + r], s);
            }
        } else { // EPI_PVOUT (unused in gemmW dispatches, kept for symmetry)
            float linv[4];
            #pragma unroll
            for (int r = 0; r < 4; ++r)
                linv[r] = 1.0f / lsum[(size_t)z * 2048 + row + r];
            #pragma unroll
            for (int ni = 0; ni < 4; ++ni) {
                const int col = n0 + wn * 64 + ni * 16 + lrow;
                const float bb = bias[col];
                const f32x4 a = acc[mi][ni];
                #pragma unroll
                for (int r = 0; r < 4; ++r)
                    Cfz[(size_t)(row + r) * LDC + col] = a[r] * linv[r] + bb;
            }
        }
    }
}

// ---------------------------------------------------------------------------
// gemm4w: R13's proven 128x128-tile 4-wave kernel (2 blocks/CU, BK=64
// double-buffered, counted vmcnt(8)) + XCD swizzle. Used for PV.
template<int EPI, int K, int LDA, int LDB, int LDC, int GX, int GY, int GZ>
__global__ __launch_bounds__(256, 2) void gemm4w(
    const u16* __restrict__ A, const u16* __restrict__ Bt,
    const float* __restrict__ bias, u16* __restrict__ C,
    float* __restrict__ Cf, float* __restrict__ lsum,
    float scale, long sA, long sB, long sC)
{
    __shared__ u16 lds[2][2][8192];   // [dbuf][A/B][128x64], 64 KiB

    constexpr int NT = K / 64;

    int bx, by, z, rawlin;
    swz_work<GX, GY, GZ>(bx, by, z, rawlin);
    (void)rawlin;

    const int t = threadIdx.x;                 // 0..255
    const int wid = t >> 6, lane = t & 63;
    const int wm = wid >> 1, wn = wid & 1;     // wave tile: 64x64 at (wm,wn)
    const int lrow = lane & 15, quad = lane >> 4;
    const int m0 = by * 128, n0 = bx * 128;

    const u16* ABase = A  + (size_t)z * sA + (size_t)m0 * LDA;
    const u16* BBase = Bt + (size_t)z * sB + (size_t)n0 * LDB;

    int srow[4], scolOff[4];
    #pragma unroll
    for (int p = 0; p < 4; ++p) {
        const int s = p * 256 + t, row = s >> 3, c8 = (s & 7) ^ (row & 7);
        srow[p] = row; scolOff[p] = c8 * 8;
    }

    auto stage = [&](int tile, int buf) {
        const int k0 = tile * 64;
        #pragma unroll
        for (int p = 0; p < 4; ++p) {
            const int s = p * 256 + t;
            async16(&lds[buf][0][s * 8],
                    ABase + (size_t)srow[p] * LDA + k0 + scolOff[p]);
        }
        #pragma unroll
        for (int p = 0; p < 4; ++p) {
            const int s = p * 256 + t;
            async16(&lds[buf][1][s * 8],
                    BBase + (size_t)srow[p] * LDB + k0 + scolOff[p]);
        }
    };

    f32x4 acc[4][4];
    #pragma unroll
    for (int i = 0; i < 4; ++i)
        #pragma unroll
        for (int j = 0; j < 4; ++j)
            acc[i][j] = (f32x4){0.f, 0.f, 0.f, 0.f};

    auto ldA1 = [&](int buf, int mi, int ks) -> bf16x8 {
        int b = (wm * 64 + mi * 16 + lrow) * 128 + ks * 64 + quad * 16;
        b ^= ((b >> 7) & 7) << 4;
        return *(const bf16x8*)((const char*)&lds[buf][0][0] + b);
    };
    auto ldB1 = [&](int buf, int ni, int ks) -> bf16x8 {
        int b = (wn * 64 + ni * 16 + lrow) * 128 + ks * 64 + quad * 16;
        b ^= ((b >> 7) & 7) << 4;
        return *(const bf16x8*)((const char*)&lds[buf][1][0] + b);
    };

    stage(0, 0);
    stage(1, 1);

    #pragma unroll 1
    for (int T = 0; T < NT; ++T) {
        const int buf = T & 1;
        if (T + 1 < NT) asm volatile("s_waitcnt vmcnt(8)" ::: "memory");
        else            asm volatile("s_waitcnt vmcnt(0)" ::: "memory");
        __builtin_amdgcn_s_barrier();

        #pragma unroll
        for (int ks = 0; ks < 2; ++ks) {
            bf16x8 aF[4], bF[4];
            #pragma unroll
            for (int mi = 0; mi < 4; ++mi) aF[mi] = ldA1(buf, mi, ks);
            #pragma unroll
            for (int ni = 0; ni < 4; ++ni) bF[ni] = ldB1(buf, ni, ks);
            __builtin_amdgcn_s_setprio(1);
            #pragma unroll
            for (int mi = 0; mi < 4; ++mi)
                #pragma unroll
                for (int ni = 0; ni < 4; ++ni)
                    acc[mi][ni] = __builtin_amdgcn_mfma_f32_16x16x32_bf16(
                        aF[mi], bF[ni], acc[mi][ni], 0, 0, 0);
            __builtin_amdgcn_s_setprio(0);
        }
        FENCE();
        __builtin_amdgcn_s_barrier();
        if (T + 2 < NT) stage(T + 2, buf);
    }

    u16*   Cz  = C  + (size_t)z * sC;
    float* Cfz = Cf ? Cf + (size_t)z * sC : nullptr;

    #pragma unroll
    for (int mi = 0; mi < 4; ++mi) {
        const int row = m0 + wm * 64 + mi * 16 + quad * 4;
        if (EPI == EPI_PVOUT) {
            float linv[4];
            #pragma unroll
            for (int r = 0; r < 4; ++r)
                linv[r] = 1.0f / lsum[(size_t)z * 2048 + row + r];
            #pragma unroll
            for (int ni = 0; ni < 4; ++ni) {
                const int col = n0 + wn * 64 + ni * 16 + lrow;
                const float bb = bias[col];
                const f32x4 a = acc[mi][ni];
                #pragma unroll
                for (int r = 0; r < 4; ++r)
                    Cfz[(size_t)(row + r) * LDC + col] = a[r] * linv[r] + bb;
            }
        } else { // EPI_BF16 fallback (unused here)
            #pragma unroll
            for (int ni = 0; ni < 4; ++ni) {
                const int col = n0 + wn * 64 + ni * 16 + lrow;
                const f32x4 a = acc[mi][ni];
                #pragma unroll
                for (int r = 0; r < 4; ++r)
                    Cz[(size_t)(row + r) * LDC + col] = f2bf(a[r]);
            }
        }
    }
}

// ---------------------------------------------------------------------------
extern "C" void kernel_launch(void* const* d_in, const int* in_sizes, int n_in,
                              void* d_out, int out_size, void* d_ws, size_t ws_size,
                              hipStream_t stream)
{
    const float* x  = (const float*)d_in[0];
    const float* wq = (const float*)d_in[1];
    const float* bq = (const float*)d_in[2];
    const float* wk = (const float*)d_in[3];
    const float* bk = (const float*)d_in[4];
    const float* wv = (const float*)d_in[5];
    const float* bv = (const float*)d_in[6];
    const float* wo = (const float*)d_in[7];
    const float* bo = (const float*)d_in[8];
    float* out = (float*)d_out;

    u16* w16   = (u16*)d_ws;
    u16* xb    = w16;
    u16* qkv   = w16 + 8388608;          // [8192][3072]; q|k|v at col 0/1024/2048
    u16* E     = w16 + 33554432;
    u16* wqkvT = w16 + 50331648;         // [3072][1024] = wqT|wkT|wvT
    u16* woT   = w16 + 53477376;
    float* bqkv = (float*)(w16 + 54525952);
    float* l    = (float*)(w16 + 54532096);
    u16* VWoT  = w16;                    // aliases xb (dead after QKV) [b][1024][2048]

    const u16* q_ = qkv;                 // LDA/LDB = 3072 views
    const u16* k_ = qkv + 1024;
    const u16* v_ = qkv + 2048;

    cast_x_kernel<<<8236, dim3(256), 0, stream>>>(x, xb, bq, bk, bv, bqkv, l);
    transpose_cast_all<<<dim3(32, 32, 4), dim3(32, 8), 0, stream>>>(
        wq, wk, wv, wo, wqkvT, woT);

    // fused QKV: qkv[8192,3072] = xb @ wqkvT^T + bqkv  (24x32 = 768 blk, 1 pass)
    gemmW<EPI_BF16BIAS, 1024, 1024, 1024, 3072, 24, 32, 1>
        <<<dim3(24, 32, 1), dim3(256), 0, stream>>>(
            xb, wqkvT, bqkv, qkv, nullptr, nullptr, 1.f, 0, 0, 0);

    // E[z] = exp((q[z] @ k[z]^T)/32) bf16, + row sums into l  (512 blocks)
    gemmW<EPI_ELOGIT, 1024, 3072, 3072, 2048, 16, 8, 4>
        <<<dim3(16, 8, 4), dim3(256), 0, stream>>>(
            q_, k_, nullptr, E, nullptr, l, 0.03125f,
            6291456, 6291456, 4194304);

    // VWoT[z] = woT @ v[z]^T   [1024][2048] bf16 per batch  (256 blocks)
    gemmW<EPI_BF16, 1024, 1024, 3072, 2048, 16, 4, 4>
        <<<dim3(16, 4, 4), dim3(256), 0, stream>>>(
            woT, v_, nullptr, VWoT, nullptr, nullptr, 1.f,
            0, 6291456, 2097152);

    // out[z] = (E[z] @ VWoT[z]^T) / l + bo   fp32 [2048][1024]  (512 blocks)
    gemm4w<EPI_PVOUT, 2048, 2048, 2048, 1024, 8, 16, 4>
        <<<dim3(8, 16, 4), dim3(256), 0, stream>>>(
            E, VWoT, bo, nullptr, out, l, 1.f,
            4194304, 2097152, 2097152);
}

// Round 10
// 404.804 us; speedup vs baseline: 1.9949x; 1.9949x over previous
//
#include <hip/hip_runtime.h>

// Self-attention fwd: B=4, S=2048, D=1024, single head.
// Round 18 = R13 base (best; 273.9us; the only L2-clean geometry: 128x128
// tile, 2 blocks/CU, multi-pass grids) + ONE change: B bypasses LDS.
//   gemmW re-test (R17) failed again: 768 co-resident blocks make each XCD's
//   live working set ~8MB > 4MB L2 regardless of ID swizzle (FETCH 485MB,
//   WRITE 531MB of write-allocate churn). Grid geometry is now frozen at R13.
//   R13 limiter: 3000cyc/CU-tile-pair = MFMA 1241 || LDS ~1750 || VMEM ~860,
//   LDS-unit dominated. Fix: load bF fragments straight from global to VGPR
//   (pattern per (ni,ks): 64 lanes = 16 rows x 64B fully-used lines -> clean
//   L2 requests; 2x wm-redundancy served by L2). LDS halves to A-only dbuf
//   (32KB): LDS term ~1750 -> ~1000. bF single register set (+32 VGPR ~116,
//   under the 128 cap; loads issued AFTER the post-MFMA barrier -> no WAR
//   renaming -> no R15-style spill).
//   vmcnt: iter end issues [loadB(T+1):8][stage(T+2):4] (FENCE-ordered);
//   iter top vmcnt(4) retires B(T)+A(T+1)... i.e. exactly keeps the 4 newest
//   (next A-stage) in flight; tail vmcnt(0).
// Epilogues, grids, ws layout identical to R13.
//
// ws layout (bf16-element offsets over (u16*)d_ws):
//   xb    @ 0          (8388608)   <- VWoT after QKV (xb dead)  [b][do][s]
//   qkv   @ 8388608    (25165824)  [8192][3072] (q|k|v interleaved by col)
//   E     @ 33554432   (16777216)  exp(logits) bf16
//   wqkvT @ 50331648   (3145728)   [3072][1024]  (wqT|wkT|wvT)
//   woT   @ 53477376   (1048576)
//   bqkv  @ 54525952   (6144 u16 = 3072 fp32)
//   l     @ 54532096   (16384 u16 = 8192 fp32 row sums)   end = 109.1 MB

typedef unsigned short u16;
typedef short bf16x8 __attribute__((ext_vector_type(8)));
typedef float f32x4 __attribute__((ext_vector_type(4)));

#define SEQ 2048
#define DIM 1024

__device__ __forceinline__ u16 f2bf(float f) {
    unsigned u = __builtin_bit_cast(unsigned, f);
    u += 0x7fffu + ((u >> 16) & 1u);
    return (u16)(u >> 16);
}

// async 16B global -> LDS (wave-uniform LDS base + lane*16 by construction)
__device__ __forceinline__ void async16(void* lds, const void* gmem) {
    __builtin_amdgcn_global_load_lds(
        (const __attribute__((address_space(1))) void*)gmem,
        (__attribute__((address_space(3))) void*)lds, 16, 0, 0);
}

#define FENCE() asm volatile("" ::: "memory")

// ---------------------------------------------------------------------------
// cast x fp32 -> bf16 (blocks 0..8191); bias concat + zero l (blocks 8192+)
__global__ __launch_bounds__(256) void cast_x_kernel(
    const float* __restrict__ x, u16* __restrict__ xb,
    const float* __restrict__ bq, const float* __restrict__ bk,
    const float* __restrict__ bv, float* __restrict__ bqkv,
    float* __restrict__ l)
{
    const int b = blockIdx.x;
    if (b < 8192) {
        const int idx = b * 256 + threadIdx.x;
        float4 v = ((const float4*)x)[idx];
        ushort4 o;
        o.x = f2bf(v.x); o.y = f2bf(v.y); o.z = f2bf(v.z); o.w = f2bf(v.w);
        ((ushort4*)xb)[idx] = o;
    } else {
        const int i = (b - 8192) * 256 + threadIdx.x;   // 0..11263
        if (i < 3072)
            bqkv[i] = (i < 1024) ? bq[i] : (i < 2048) ? bk[i - 1024] : bv[i - 2048];
        else if (i < 3072 + 8192)
            l[i - 3072] = 0.f;
    }
}

// transpose+cast all four 1024x1024 fp32 weights -> bf16 WT[n][k]; z picks W.
__global__ __launch_bounds__(256) void transpose_cast_all(
    const float* __restrict__ W0, const float* __restrict__ W1,
    const float* __restrict__ W2, const float* __restrict__ W3,
    u16* __restrict__ Tqkv, u16* __restrict__ To)
{
    __shared__ float tile[32][33];
    const int z = blockIdx.z;
    const float* W = (z == 0) ? W0 : (z == 1) ? W1 : (z == 2) ? W2 : W3;
    u16* T = (z < 3) ? (Tqkv + (size_t)z * 1048576) : To;

    const int bx = blockIdx.x * 32, by = blockIdx.y * 32;
    const int tx = threadIdx.x, ty = threadIdx.y;
    #pragma unroll
    for (int r = 0; r < 4; ++r)
        tile[ty + r * 8][tx] = W[(size_t)(by + ty + r * 8) * DIM + bx + tx];
    __syncthreads();
    #pragma unroll
    for (int r = 0; r < 4; ++r) {
        const float v = tile[tx][ty + r * 8];   // = W[by+tx][bx+ty+r*8]
        T[(size_t)(bx + ty + r * 8) * DIM + by + tx] = f2bf(v);
    }
}

// ---------------------------------------------------------------------------
// 128x128-tile 4-wave GEMM: A[M,K] @ Bt[N,K]^T. 2 blocks/CU (32 KiB LDS).
// A staged via global_load_lds (dbuf, XOR-swizzled); B loaded straight to
// registers from L2.
#define EPI_BF16BIAS 0  // bf16 store of a+bias[col]
#define EPI_BF16     1  // bf16 store of a
#define EPI_ELOGIT   2  // store exp(a*scale) bf16 + atomic row sums into lsum
#define EPI_PVOUT    3  // fp32 store of a/lsum[row] + bias[col]

template<int EPI, int K, int LDA, int LDB, int LDC>
__global__ __launch_bounds__(256, 2) void gemm4w(
    const u16* __restrict__ A, const u16* __restrict__ Bt,
    const float* __restrict__ bias, u16* __restrict__ C,
    float* __restrict__ Cf, float* __restrict__ lsum,
    float scale, long sA, long sB, long sC)
{
    // [dbuf] A-tile 128x64 bf16, 16 KB each = 32 KiB total.
    __shared__ u16 lds[2][8192];

    constexpr int NT = K / 64;      // 64-wide K tiles (>= 2)

    const int z = blockIdx.z;
    const int t = threadIdx.x;                 // 0..255
    const int wid = t >> 6, lane = t & 63;
    const int wm = wid >> 1, wn = wid & 1;     // wave tile: 64x64 at (wm,wn)
    const int lrow = lane & 15, quad = lane >> 4;
    const int m0 = blockIdx.y * 128, n0 = blockIdx.x * 128;

    const u16* ABase = A  + (size_t)z * sA + (size_t)m0 * LDA;
    const u16* BBase = Bt + (size_t)z * sB + (size_t)n0 * LDB;

    // A staging: 1024 16B chunks per 128x64 tile; thread owns 4. LDS dest
    // linear (global_load_lds constraint); global SOURCE chunk column is
    // pre-swizzled with the read involution chunk ^= (row&7)
    // (byte bits 4-6 ^= row bits 0-2; rows are 128 B).
    int srow[4], scolOff[4];
    #pragma unroll
    for (int p = 0; p < 4; ++p) {
        const int s = p * 256 + t, row = s >> 3, c8 = (s & 7) ^ (row & 7);
        srow[p] = row; scolOff[p] = c8 * 8;
    }

    auto stage = [&](int tile, int buf) {
        const int k0 = tile * 64;
        #pragma unroll
        for (int p = 0; p < 4; ++p) {
            const int s = p * 256 + t;
            async16(&lds[buf][s * 8],
                    ABase + (size_t)srow[p] * LDA + k0 + scolOff[p]);
        }
    };

    // B fragments: straight global->VGPR. Lane reads 16B at
    // B[n0 + wn*64 + ni*16 + lrow][k0 + ks*32 + quad*8]: per (ni,ks) the wave
    // covers 16 rows x 64 contiguous bytes (fully-used lines).
    bf16x8 bF[4][2];
    auto loadB = [&](int tile) {
        const int k0 = tile * 64;
        #pragma unroll
        for (int ni = 0; ni < 4; ++ni)
            #pragma unroll
            for (int ks = 0; ks < 2; ++ks)
                bF[ni][ks] = *(const bf16x8*)(BBase
                    + (size_t)(wn * 64 + ni * 16 + lrow) * LDB
                    + k0 + ks * 32 + quad * 8);
    };

    f32x4 acc[4][4];
    #pragma unroll
    for (int i = 0; i < 4; ++i)
        #pragma unroll
        for (int j = 0; j < 4; ++j)
            acc[i][j] = (f32x4){0.f, 0.f, 0.f, 0.f};

    // swizzled ds_read of one 16x16x32 A fragment (16B per lane)
    auto ldA1 = [&](int buf, int mi, int ks) -> bf16x8 {
        int b = (wm * 64 + mi * 16 + lrow) * 128 + ks * 64 + quad * 16;
        b ^= ((b >> 7) & 7) << 4;
        return *(const bf16x8*)((const char*)&lds[buf][0] + b);
    };

    // ---- prologue: bF(0) + A tiles 0,1 in flight ----
    loadB(0);
    FENCE();                       // keep B(0) older than A stages in queue
    stage(0, 0);
    stage(1, 1);

    #pragma unroll 1
    for (int T = 0; T < NT; ++T) {
        const int buf = T & 1;
        // outstanding at top: [B(T):8, A(T+1):4]; vmcnt(4) retires B(T) and
        // everything older (incl. A(T)), keeps next A-stage in flight.
        if (T + 1 < NT) asm volatile("s_waitcnt vmcnt(4)" ::: "memory");
        else            asm volatile("s_waitcnt vmcnt(0)" ::: "memory");
        __builtin_amdgcn_s_barrier();

        #pragma unroll
        for (int ks = 0; ks < 2; ++ks) {
            bf16x8 aF[4];
            #pragma unroll
            for (int mi = 0; mi < 4; ++mi) aF[mi] = ldA1(buf, mi, ks);
            __builtin_amdgcn_s_setprio(1);
            #pragma unroll
            for (int mi = 0; mi < 4; ++mi)
                #pragma unroll
                for (int ni = 0; ni < 4; ++ni)
                    acc[mi][ni] = __builtin_amdgcn_mfma_f32_16x16x32_bf16(
                        aF[mi], bF[ni][ks], acc[mi][ni], 0, 0, 0);
            __builtin_amdgcn_s_setprio(0);
        }
        FENCE();
        __builtin_amdgcn_s_barrier();   // A(T) reads drained -> restage safe
        if (T + 1 < NT) loadB(T + 1);   // bF dead after MFMA cluster (no WAR)
        FENCE();                        // order: B(T+1) before A(T+2) in queue
        if (T + 2 < NT) stage(T + 2, buf);
    }

    // ---- epilogue ----
    u16*   Cz  = C  + (size_t)z * sC;
    float* Cfz = Cf ? Cf + (size_t)z * sC : nullptr;

    #pragma unroll
    for (int mi = 0; mi < 4; ++mi) {
        const int row = m0 + wm * 64 + mi * 16 + quad * 4;   // rows row..row+3
        if (EPI == EPI_BF16BIAS) {
            #pragma unroll
            for (int ni = 0; ni < 4; ++ni) {
                const int col = n0 + wn * 64 + ni * 16 + lrow;
                const float bb = bias[col];
                const f32x4 a = acc[mi][ni];
                #pragma unroll
                for (int r = 0; r < 4; ++r)
                    Cz[(size_t)(row + r) * LDC + col] = f2bf(a[r] + bb);
            }
        } else if (EPI == EPI_BF16) {
            #pragma unroll
            for (int ni = 0; ni < 4; ++ni) {
                const int col = n0 + wn * 64 + ni * 16 + lrow;
                const f32x4 a = acc[mi][ni];
                #pragma unroll
                for (int r = 0; r < 4; ++r)
                    Cz[(size_t)(row + r) * LDC + col] = f2bf(a[r]);
            }
        } else if (EPI == EPI_ELOGIT) {
            float rs[4] = {0.f, 0.f, 0.f, 0.f};
            #pragma unroll
            for (int ni = 0; ni < 4; ++ni) {
                const int col = n0 + wn * 64 + ni * 16 + lrow;
                const f32x4 a = acc[mi][ni];
                #pragma unroll
                for (int r = 0; r < 4; ++r) {
                    const float e = __expf(a[r] * scale);
                    Cz[(size_t)(row + r) * LDC + col] = f2bf(e);
                    rs[r] += e;
                }
            }
            #pragma unroll
            for (int r = 0; r < 4; ++r) {
                float s = rs[r];
                s += __shfl_xor(s, 1, 64);
                s += __shfl_xor(s, 2, 64);
                s += __shfl_xor(s, 4, 64);
                s += __shfl_xor(s, 8, 64);
                if (lrow == 0)
                    atomicAdd(&lsum[(size_t)z * 2048 + row + r], s);
            }
        } else { // EPI_PVOUT
            float linv[4];
            #pragma unroll
            for (int r = 0; r < 4; ++r)
                linv[r] = 1.0f / lsum[(size_t)z * 2048 + row + r];
            #pragma unroll
            for (int ni = 0; ni < 4; ++ni) {
                const int col = n0 + wn * 64 + ni * 16 + lrow;
                const float bb = bias[col];
                const f32x4 a = acc[mi][ni];
                #pragma unroll
                for (int r = 0; r < 4; ++r)
                    Cfz[(size_t)(row + r) * LDC + col] = a[r] * linv[r] + bb;
            }
        }
    }
}

// ---------------------------------------------------------------------------
extern "C" void kernel_launch(void* const* d_in, const int* in_sizes, int n_in,
                              void* d_out, int out_size, void* d_ws, size_t ws_size,
                              hipStream_t stream)
{
    const float* x  = (const float*)d_in[0];
    const float* wq = (const float*)d_in[1];
    const float* bq = (const float*)d_in[2];
    const float* wk = (const float*)d_in[3];
    const float* bk = (const float*)d_in[4];
    const float* wv = (const float*)d_in[5];
    const float* bv = (const float*)d_in[6];
    const float* wo = (const float*)d_in[7];
    const float* bo = (const float*)d_in[8];
    float* out = (float*)d_out;

    u16* w16   = (u16*)d_ws;
    u16* xb    = w16;
    u16* qkv   = w16 + 8388608;          // [8192][3072]; q|k|v at col 0/1024/2048
    u16* E     = w16 + 33554432;
    u16* wqkvT = w16 + 50331648;         // [3072][1024] = wqT|wkT|wvT
    u16* woT   = w16 + 53477376;
    float* bqkv = (float*)(w16 + 54525952);
    float* l    = (float*)(w16 + 54532096);
    u16* VWoT  = w16;                    // aliases xb (dead after QKV) [b][do][s]

    const u16* q_ = qkv;                 // LDA/LDB = 3072 views
    const u16* k_ = qkv + 1024;
    const u16* v_ = qkv + 2048;

    cast_x_kernel<<<8236, dim3(256), 0, stream>>>(x, xb, bq, bk, bv, bqkv, l);
    transpose_cast_all<<<dim3(32, 32, 4), dim3(32, 8), 0, stream>>>(
        wq, wk, wv, wo, wqkvT, woT);

    // fused QKV: qkv[8192,3072] = xb @ wqkvT^T + bqkv   (24x64 = 1536 blocks)
    gemm4w<EPI_BF16BIAS, 1024, 1024, 1024, 3072>
        <<<dim3(24, 64, 1), dim3(256), 0, stream>>>(
            xb, wqkvT, bqkv, qkv, nullptr, nullptr, 1.f, 0, 0, 0);

    // E[z] = exp((q[z] @ k[z]^T)/32) bf16, + row sums into l  (1024 blocks)
    gemm4w<EPI_ELOGIT, 1024, 3072, 3072, 2048>
        <<<dim3(16, 16, 4), dim3(256), 0, stream>>>(
            q_, k_, nullptr, E, nullptr, l, 0.03125f,
            6291456, 6291456, 4194304);

    // VWoT[z] = woT @ v[z]^T   [1024][2048] bf16 per batch  (512 blocks)
    gemm4w<EPI_BF16, 1024, 1024, 3072, 2048>
        <<<dim3(16, 8, 4), dim3(256), 0, stream>>>(
            woT, v_, nullptr, VWoT, nullptr, nullptr, 1.f,
            0, 6291456, 2097152);

    // out[z] = (E[z] @ VWoT[z]^T) / l + bo   fp32 [2048][1024]  (512 blocks)
    gemm4w<EPI_PVOUT, 2048, 2048, 2048, 1024>
        <<<dim3(8, 16, 4), dim3(256), 0, stream>>>(
            E, VWoT, bo, nullptr, out, l, 1.f,
            4194304, 2097152, 2097152);
}

// Round 11
// 294.701 us; speedup vs baseline: 2.7402x; 1.3736x over previous
//
#include <hip/hip_runtime.h>

// Self-attention fwd: B=4, S=2048, D=1024, single head.
// Round 19: revert R18 (B-from-global exposed L2 latency every tile: 118us,
// MfmaUtil 17.5%). Back to R13's staging discipline + reshape for fewer
// stalls per round at IDENTICAL FLOP/round:
//   - 2-wave blocks (128 thr), wave = 64x128 output (acc 4x8), BK=32,
//     LDS [dbuf][A|B][128x32] = 32 KB/block -> 4 blocks/CU (8 waves/CU,
//     2/SIMD -- same as R13).
//   - Per CU-round (8 waves x 1 tile): MFMA 1241 cyc/SIMD (same as R13) but
//     LDS reads 128->96 KB, ONE lgkm batch of 12 reads per wave (was 2x8),
//     32-MFMA runs (was 16), 2-wave barriers (was 4).
//   - Staging/vmcnt byte-identical discipline to R13: counted vmcnt(8) at
//     iter top (tile T+1 stays in flight), stage(T+2) only after the
//     post-MFMA barrier (all reads of that buffer provably drained), tail
//     vmcnt(0). NO stagger: R14/R17/R18 taught that the loose lockstep this
//     enforces is what keeps the per-XCD K-slice working set L2-resident.
//   - 64-B LDS rows -> new swizzle byte ^= ((byte>>7)&3)<<4 (chunk bits 4-5
//     ^= row bits 1-2): 2 lanes/bank under the quarter-wave phase model that
//     explains measured-0 conflicts at 128-B rows. Source pre-swizzled with
//     the same involution (c4 = (slot&3) ^ ((row>>1)&3)).
// Epilogues + associativity rewrite out = P @ (V*Wo) + grids kept from R13.
//
// ws layout (bf16-element offsets over (u16*)d_ws):
//   xb    @ 0          (8388608)   <- VWoT after QKV (xb dead)  [b][do][s]
//   qkv   @ 8388608    (25165824)  [8192][3072] (q|k|v interleaved by col)
//   E     @ 33554432   (16777216)  exp(logits) bf16
//   wqkvT @ 50331648   (3145728)   [3072][1024]  (wqT|wkT|wvT)
//   woT   @ 53477376   (1048576)
//   bqkv  @ 54525952   (6144 u16 = 3072 fp32)
//   l     @ 54532096   (16384 u16 = 8192 fp32 row sums)   end = 109.1 MB

typedef unsigned short u16;
typedef short bf16x8 __attribute__((ext_vector_type(8)));
typedef float f32x4 __attribute__((ext_vector_type(4)));

#define SEQ 2048
#define DIM 1024

__device__ __forceinline__ u16 f2bf(float f) {
    unsigned u = __builtin_bit_cast(unsigned, f);
    u += 0x7fffu + ((u >> 16) & 1u);
    return (u16)(u >> 16);
}

// async 16B global -> LDS (wave-uniform LDS base + lane*16 by construction)
__device__ __forceinline__ void async16(void* lds, const void* gmem) {
    __builtin_amdgcn_global_load_lds(
        (const __attribute__((address_space(1))) void*)gmem,
        (__attribute__((address_space(3))) void*)lds, 16, 0, 0);
}

#define FENCE() asm volatile("" ::: "memory")

// ---------------------------------------------------------------------------
// cast x fp32 -> bf16 (blocks 0..8191); bias concat + zero l (blocks 8192+)
__global__ __launch_bounds__(256) void cast_x_kernel(
    const float* __restrict__ x, u16* __restrict__ xb,
    const float* __restrict__ bq, const float* __restrict__ bk,
    const float* __restrict__ bv, float* __restrict__ bqkv,
    float* __restrict__ l)
{
    const int b = blockIdx.x;
    if (b < 8192) {
        const int idx = b * 256 + threadIdx.x;
        float4 v = ((const float4*)x)[idx];
        ushort4 o;
        o.x = f2bf(v.x); o.y = f2bf(v.y); o.z = f2bf(v.z); o.w = f2bf(v.w);
        ((ushort4*)xb)[idx] = o;
    } else {
        const int i = (b - 8192) * 256 + threadIdx.x;   // 0..11263
        if (i < 3072)
            bqkv[i] = (i < 1024) ? bq[i] : (i < 2048) ? bk[i - 1024] : bv[i - 2048];
        else if (i < 3072 + 8192)
            l[i - 3072] = 0.f;
    }
}

// transpose+cast all four 1024x1024 fp32 weights -> bf16 WT[n][k]; z picks W.
__global__ __launch_bounds__(256) void transpose_cast_all(
    const float* __restrict__ W0, const float* __restrict__ W1,
    const float* __restrict__ W2, const float* __restrict__ W3,
    u16* __restrict__ Tqkv, u16* __restrict__ To)
{
    __shared__ float tile[32][33];
    const int z = blockIdx.z;
    const float* W = (z == 0) ? W0 : (z == 1) ? W1 : (z == 2) ? W2 : W3;
    u16* T = (z < 3) ? (Tqkv + (size_t)z * 1048576) : To;

    const int bx = blockIdx.x * 32, by = blockIdx.y * 32;
    const int tx = threadIdx.x, ty = threadIdx.y;
    #pragma unroll
    for (int r = 0; r < 4; ++r)
        tile[ty + r * 8][tx] = W[(size_t)(by + ty + r * 8) * DIM + bx + tx];
    __syncthreads();
    #pragma unroll
    for (int r = 0; r < 4; ++r) {
        const float v = tile[tx][ty + r * 8];   // = W[by+tx][bx+ty+r*8]
        T[(size_t)(bx + ty + r * 8) * DIM + by + tx] = f2bf(v);
    }
}

// ---------------------------------------------------------------------------
// 128x128-tile 2-wave GEMM: A[M,K] @ Bt[N,K]^T. 4 blocks/CU (32 KiB LDS).
// Wave w owns rows [w*64, w*64+64) x all 128 cols (acc 4x8).
#define EPI_BF16BIAS 0  // bf16 store of a+bias[col]
#define EPI_BF16     1  // bf16 store of a
#define EPI_ELOGIT   2  // store exp(a*scale) bf16 + atomic row sums into lsum
#define EPI_PVOUT    3  // fp32 store of a/lsum[row] + bias[col]

template<int EPI, int K, int LDA, int LDB, int LDC>
__global__ __launch_bounds__(128, 2) void gemm2x(
    const u16* __restrict__ A, const u16* __restrict__ Bt,
    const float* __restrict__ bias, u16* __restrict__ C,
    float* __restrict__ Cf, float* __restrict__ lsum,
    float scale, long sA, long sB, long sC)
{
    // [dbuf][mat(A/B)][128x32 bf16] = 8 KB each, 32 KiB total.
    __shared__ u16 lds[2][2][4096];

    constexpr int NT = K / 32;      // 32-wide K tiles (>= 4)
    static_assert(NT >= 4, "K >= 128");

    const int z = blockIdx.z;
    const int t = threadIdx.x;                 // 0..127
    const int w = t >> 6, lane = t & 63;       // wave 0/1 -> rows w*64..+63
    const int lrow = lane & 15, quad = lane >> 4;
    const int m0 = blockIdx.y * 128, n0 = blockIdx.x * 128;

    const u16* ABase = A  + (size_t)z * sA + (size_t)m0 * LDA;
    const u16* BBase = Bt + (size_t)z * sB + (size_t)n0 * LDB;

    // staging: 512 16B chunks per 128x32 tile-mat; thread owns 4 per mat.
    // LDS dest linear (global_load_lds constraint); global SOURCE chunk is
    // pre-swizzled with the read involution c4 ^= (row>>1)&3
    // (byte bits 4-5 ^= row bits 1-2; rows are 64 B).
    int offA[4], offB[4];
    #pragma unroll
    for (int p = 0; p < 4; ++p) {
        const int s = p * 128 + t;             // 0..511
        const int row = s >> 2;                // 0..127
        const int c4 = (s & 3) ^ ((row >> 1) & 3);
        offA[p] = row * LDA + c4 * 8;
        offB[p] = row * LDB + c4 * 8;
    }

    auto stage = [&](int tile, int buf) {
        const int k0 = tile * 32;
        #pragma unroll
        for (int p = 0; p < 4; ++p)
            async16(&lds[buf][0][(p * 128 + t) * 8], ABase + k0 + offA[p]);
        #pragma unroll
        for (int p = 0; p < 4; ++p)
            async16(&lds[buf][1][(p * 128 + t) * 8], BBase + k0 + offB[p]);
    };

    f32x4 acc[4][8];
    #pragma unroll
    for (int i = 0; i < 4; ++i)
        #pragma unroll
        for (int j = 0; j < 8; ++j)
            acc[i][j] = (f32x4){0.f, 0.f, 0.f, 0.f};

    // swizzled ds_read of one 16x16x32 fragment (16B per lane)
    auto ldA1 = [&](int buf, int mi) -> bf16x8 {
        int b = (w * 64 + mi * 16 + lrow) * 64 + quad * 16;
        b ^= ((b >> 7) & 3) << 4;
        return *(const bf16x8*)((const char*)&lds[buf][0][0] + b);
    };
    auto ldB1 = [&](int buf, int ni) -> bf16x8 {
        int b = (ni * 16 + lrow) * 64 + quad * 16;
        b ^= ((b >> 7) & 3) << 4;
        return *(const bf16x8*)((const char*)&lds[buf][1][0] + b);
    };

    // ---- prologue: tiles 0,1 in flight (8 wave-loads each) ----
    stage(0, 0);
    stage(1, 1);

    #pragma unroll 1
    for (int T = 0; T < NT; ++T) {
        const int buf = T & 1;
        // retire tile T's 8 loads; keep T+1's 8 in flight (counted, not 0)
        if (T + 1 < NT) asm volatile("s_waitcnt vmcnt(8)" ::: "memory");
        else            asm volatile("s_waitcnt vmcnt(0)" ::: "memory");
        __builtin_amdgcn_s_barrier();

        bf16x8 aF[4], bF[8];
        #pragma unroll
        for (int mi = 0; mi < 4; ++mi) aF[mi] = ldA1(buf, mi);
        #pragma unroll
        for (int ni = 0; ni < 8; ++ni) bF[ni] = ldB1(buf, ni);
        __builtin_amdgcn_s_setprio(1);
        #pragma unroll
        for (int mi = 0; mi < 4; ++mi)
            #pragma unroll
            for (int ni = 0; ni < 8; ++ni)
                acc[mi][ni] = __builtin_amdgcn_mfma_f32_16x16x32_bf16(
                    aF[mi], bF[ni], acc[mi][ni], 0, 0, 0);
        __builtin_amdgcn_s_setprio(0);

        FENCE();
        __builtin_amdgcn_s_barrier();   // buf's reads drained -> safe restage
        if (T + 2 < NT) stage(T + 2, buf);
    }

    // ---- epilogue ----
    u16*   Cz  = C  + (size_t)z * sC;
    float* Cfz = Cf ? Cf + (size_t)z * sC : nullptr;

    #pragma unroll
    for (int mi = 0; mi < 4; ++mi) {
        const int row = m0 + w * 64 + mi * 16 + quad * 4;    // rows row..row+3
        if (EPI == EPI_BF16BIAS) {
            #pragma unroll
            for (int ni = 0; ni < 8; ++ni) {
                const int col = n0 + ni * 16 + lrow;
                const float bb = bias[col];
                const f32x4 a = acc[mi][ni];
                #pragma unroll
                for (int r = 0; r < 4; ++r)
                    Cz[(size_t)(row + r) * LDC + col] = f2bf(a[r] + bb);
            }
        } else if (EPI == EPI_BF16) {
            #pragma unroll
            for (int ni = 0; ni < 8; ++ni) {
                const int col = n0 + ni * 16 + lrow;
                const f32x4 a = acc[mi][ni];
                #pragma unroll
                for (int r = 0; r < 4; ++r)
                    Cz[(size_t)(row + r) * LDC + col] = f2bf(a[r]);
            }
        } else if (EPI == EPI_ELOGIT) {
            float rs[4] = {0.f, 0.f, 0.f, 0.f};
            #pragma unroll
            for (int ni = 0; ni < 8; ++ni) {
                const int col = n0 + ni * 16 + lrow;
                const f32x4 a = acc[mi][ni];
                #pragma unroll
                for (int r = 0; r < 4; ++r) {
                    const float e = __expf(a[r] * scale);
                    Cz[(size_t)(row + r) * LDC + col] = f2bf(e);
                    rs[r] += e;
                }
            }
            #pragma unroll
            for (int r = 0; r < 4; ++r) {
                float s = rs[r];
                s += __shfl_xor(s, 1, 64);
                s += __shfl_xor(s, 2, 64);
                s += __shfl_xor(s, 4, 64);
                s += __shfl_xor(s, 8, 64);
                if (lrow == 0)
                    atomicAdd(&lsum[(size_t)z * 2048 + row + r], s);
            }
        } else { // EPI_PVOUT
            float linv[4];
            #pragma unroll
            for (int r = 0; r < 4; ++r)
                linv[r] = 1.0f / lsum[(size_t)z * 2048 + row + r];
            #pragma unroll
            for (int ni = 0; ni < 8; ++ni) {
                const int col = n0 + ni * 16 + lrow;
                const float bb = bias[col];
                const f32x4 a = acc[mi][ni];
                #pragma unroll
                for (int r = 0; r < 4; ++r)
                    Cfz[(size_t)(row + r) * LDC + col] = a[r] * linv[r] + bb;
            }
        }
    }
}

// ---------------------------------------------------------------------------
extern "C" void kernel_launch(void* const* d_in, const int* in_sizes, int n_in,
                              void* d_out, int out_size, void* d_ws, size_t ws_size,
                              hipStream_t stream)
{
    const float* x  = (const float*)d_in[0];
    const float* wq = (const float*)d_in[1];
    const float* bq = (const float*)d_in[2];
    const float* wk = (const float*)d_in[3];
    const float* bk = (const float*)d_in[4];
    const float* wv = (const float*)d_in[5];
    const float* bv = (const float*)d_in[6];
    const float* wo = (const float*)d_in[7];
    const float* bo = (const float*)d_in[8];
    float* out = (float*)d_out;

    u16* w16   = (u16*)d_ws;
    u16* xb    = w16;
    u16* qkv   = w16 + 8388608;          // [8192][3072]; q|k|v at col 0/1024/2048
    u16* E     = w16 + 33554432;
    u16* wqkvT = w16 + 50331648;         // [3072][1024] = wqT|wkT|wvT
    u16* woT   = w16 + 53477376;
    float* bqkv = (float*)(w16 + 54525952);
    float* l    = (float*)(w16 + 54532096);
    u16* VWoT  = w16;                    // aliases xb (dead after QKV) [b][do][s]

    const u16* q_ = qkv;                 // LDA/LDB = 3072 views
    const u16* k_ = qkv + 1024;
    const u16* v_ = qkv + 2048;

    cast_x_kernel<<<8236, dim3(256), 0, stream>>>(x, xb, bq, bk, bv, bqkv, l);
    transpose_cast_all<<<dim3(32, 32, 4), dim3(32, 8), 0, stream>>>(
        wq, wk, wv, wo, wqkvT, woT);

    // fused QKV: qkv[8192,3072] = xb @ wqkvT^T + bqkv   (24x64 = 1536 blocks)
    gemm2x<EPI_BF16BIAS, 1024, 1024, 1024, 3072>
        <<<dim3(24, 64, 1), dim3(128), 0, stream>>>(
            xb, wqkvT, bqkv, qkv, nullptr, nullptr, 1.f, 0, 0, 0);

    // E[z] = exp((q[z] @ k[z]^T)/32) bf16, + row sums into l  (1024 blocks)
    gemm2x<EPI_ELOGIT, 1024, 3072, 3072, 2048>
        <<<dim3(16, 16, 4), dim3(128), 0, stream>>>(
            q_, k_, nullptr, E, nullptr, l, 0.03125f,
            6291456, 6291456, 4194304);

    // VWoT[z] = woT @ v[z]^T   [1024][2048] bf16 per batch  (512 blocks)
    gemm2x<EPI_BF16, 1024, 1024, 3072, 2048>
        <<<dim3(16, 8, 4), dim3(128), 0, stream>>>(
            woT, v_, nullptr, VWoT, nullptr, nullptr, 1.f,
            0, 6291456, 2097152);

    // out[z] = (E[z] @ VWoT[z]^T) / l + bo   fp32 [2048][1024]  (512 blocks)
    gemm2x<EPI_PVOUT, 2048, 2048, 2048, 1024>
        <<<dim3(8, 16, 4), dim3(128), 0, stream>>>(
            E, VWoT, bo, nullptr, out, l, 1.f,
            4194304, 2097152, 2097152);
}